// Round 1
// baseline (218.633 us; speedup 1.0000x reference)
//
#include <hip/hip_runtime.h>
#include <cmath>

#define T_LEN   480000
#define BATCH   64
#define CHUNK   16                       /* samples per thread */
#define WARM    16                       /* warm-up samples (|pole|=0.414 -> 0.414^16 ~ 7.6e-7) */
#define TPB     256
#define TS      (TPB * CHUNK)            /* 4096 samples per tile */
#define TPR     ((T_LEN + TS - 1) / TS)  /* 118 tiles per row */
#define NLOAD_MAX (TS + WARM)            /* 4112 */
#define NITER   ((NLOAD_MAX + TPB * 4 - 1) / (TPB * 4))   /* 5 */
/* quad skew: +4 floats per 32 -> every aligned float4 stays contiguous,
   and all three access patterns are exactly bank-uniform (8 lanes/quad). */
#define LDS_SLOTS (NLOAD_MAX + ((NLOAD_MAX >> 5) << 2))  /* 4624 = 18.5 KB */

__device__ __forceinline__ int slot4(int i) { return i + ((i >> 5) << 2); }

#define STEP(XN, YN)                                            \
    {                                                           \
        float u_ = fmaf(B0, (XN), fmaf(B1, x1, B2 * x2));       \
        (YN) = fmaf(-A1, y1, fmaf(-A2, y2, u_));                \
        x2 = x1; x1 = (XN); y2 = y1; y1 = (YN);                 \
    }

__global__ __launch_bounds__(TPB) void allpass_kernel(
    const float* __restrict__ x, float* __restrict__ y,
    float B0, float B1, float B2, float A1, float A2)
{
    __shared__ __align__(16) float lds[LDS_SLOTS];
    const int tid  = threadIdx.x;
    const int row  = blockIdx.x / TPR;
    const int tb   = blockIdx.x % TPR;
    const int sbase = tb * TS;
    const int ns   = min(TS, T_LEN - sbase);      /* 4096, last tile 768 */
    const float* __restrict__ xr = x + (size_t)row * T_LEN + sbase;
    float* __restrict__ yr       = y + (size_t)row * T_LEN + sbase;
    const int nload = ns + WARM;                  /* multiple of 4 */

    /* ---- phase 1: issue ALL global loads first (register buffer), then
       all ds_writes.  Compile-time NITER keeps the loop fully unrolled so
       the 5 float4 loads are simultaneously in flight instead of the old
       rolled loop's load->vmcnt(0)->ds_write serial round trips. ---- */
    float4 vbuf[NITER];
    #pragma unroll
    for (int j = 0; j < NITER; ++j) {
        const int i4 = tid * 4 + j * (TPB * 4);
        if (i4 < nload) {
            if (tb == 0 && i4 < WARM)
                vbuf[j] = make_float4(0.f, 0.f, 0.f, 0.f); /* state before t=0 */
            else
                vbuf[j] = *(const float4*)(xr - WARM + i4);
        }
    }
    #pragma unroll
    for (int j = 0; j < NITER; ++j) {
        const int i4 = tid * 4 + j * (TPB * 4);
        if (i4 < nload)
            *(float4*)&lds[slot4(i4)] = vbuf[j];  /* ds_write_b128, uniform */
    }
    __syncthreads();                              /* the ONLY barrier */

    /* ---- phase 2: per-thread recurrence (16 warm-up + 16 real steps),
       store y directly from registers.  A wave's 4 stores at 64B lane
       stride cover a contiguous 4KB span; L2 merges them into full lines,
       so no LDS round trip / extra barriers are needed for coalescing. ---- */
    const int ls = tid * CHUNK;                   /* output-coord start */
    if (ls < ns) {
        float x1 = 0.f, x2 = 0.f, y1 = 0.f, y2 = 0.f;
        #pragma unroll
        for (int t4 = 0; t4 < WARM; t4 += 4) {    /* coords [ls, ls+16) */
            float4 xv = *(const float4*)&lds[slot4(ls + t4)];
            float t;
            STEP(xv.x, t); STEP(xv.y, t); STEP(xv.z, t); STEP(xv.w, t);
        }
        #pragma unroll
        for (int t4 = 0; t4 < CHUNK; t4 += 4) {   /* coords [ls+16, ls+32) */
            float4 xv = *(const float4*)&lds[slot4(ls + WARM + t4)];
            float4 yv;
            STEP(xv.x, yv.x); STEP(xv.y, yv.y);
            STEP(xv.z, yv.z); STEP(xv.w, yv.w);
            *(float4*)(yr + ls + t4) = yv;        /* direct register store */
        }
    }
}

extern "C" void kernel_launch(void* const* d_in, const int* in_sizes, int n_in,
                              void* d_out, int out_size, void* d_ws, size_t ws_size,
                              hipStream_t stream) {
    const float* x = (const float*)d_in[0];
    float* y = (float*)d_out;

    const double sample_rate = 16000.0, central_freq = 4000.0, Q = 0.707;
    const double w0 = 2.0 * M_PI * central_freq / sample_rate;
    const double alpha = sin(w0) / (2.0 * Q);
    const double cw = cos(w0);
    const double a0 = 1.0 + alpha;
    const float B0 = (float)((1.0 - alpha) / a0);
    const float B1 = (float)((-2.0 * cw) / a0);
    const float B2 = (float)((1.0 + alpha) / a0);
    const float A1 = (float)((-2.0 * cw) / a0);
    const float A2 = (float)((1.0 - alpha) / a0);

    const int blocks = BATCH * TPR;   /* 7552 */
    allpass_kernel<<<blocks, TPB, 0, stream>>>(x, y, B0, B1, B2, A1, A2);
}